// Round 2
// baseline (648.444 us; speedup 1.0000x reference)
//
#include <hip/hip_runtime.h>
#include <hip/hip_bf16.h>
#include <math.h>

// Problem constants (fixed by setup_inputs): B=4, H=W=128, A=1024, C=6
#define A_DIM 1024
#define C_DIM 6
#define N_PIX 65536          // B*H*W
#define HW 16384             // H*W
#define S1_BLOCKS 512        // stage-1 partial count
#define S1_ROWS 128          // rows per stage-1 block (65536/512)

// ws float layout (accs block):
// [0..5]   Z[c]    (sum of exp(tarout) per class, accumulated in k_main)
// [6]      loss1 numerator accumulator
// [8..13]  counts[c]
// [16..21] N[c]    (sum of exp(tarout)*b per class)
// [64 ..)            Yn (6144 floats)
// [64+6144 ..)       part1 (512*6144)
// [.. +98304)        part2 (16*6144)
#define WS_ACC  0
#define WS_YN   64
#define WS_P1   (WS_YN + C_DIM * A_DIM)
#define WS_P2   (WS_P1 + S1_BLOCKS * C_DIM * A_DIM)

// ---- init: blocks 0..5 normalize Proto rows -> Yn; block 6 zeroes accumulators ----
__global__ __launch_bounds__(256) void k_init(
        const float* __restrict__ proto, float* __restrict__ yn,
        float* __restrict__ accs) {
    const int t = threadIdx.x;
    if (blockIdx.x == C_DIM) {
        if (t < 64) accs[t] = 0.0f;
        return;
    }
    const int c = blockIdx.x;
    const float* row = proto + c * A_DIM;
    float ss = 0.0f;
#pragma unroll
    for (int j = 0; j < 4; ++j) {
        float x = row[t + j * 256];
        ss = fmaf(x, x, ss);
    }
    for (int off = 32; off > 0; off >>= 1) ss += __shfl_down(ss, off, 64);
    __shared__ float sred[4];
    if ((t & 63) == 0) sred[t >> 6] = ss;
    __syncthreads();
    const float tot = sred[0] + sred[1] + sred[2] + sred[3];
    const float inv = 1.0f / fmaxf(sqrtf(tot), 1e-12f);
#pragma unroll
    for (int j = 0; j < 4; ++j) yn[c * A_DIM + t + j * 256] = row[t + j * 256] * inv;
}

// ---- per-class masked column sums of srcfeat + label histogram ----
// One float4 per thread per row: 64 lanes x 16B = 1 KiB per wave instruction.
__global__ __launch_bounds__(256) void k_src_stage1(
        const float* __restrict__ src, const int* __restrict__ labels,
        float* __restrict__ part, float* __restrict__ counts) {
    const int t = threadIdx.x;          // 0..255 -> columns 4t..4t+3
    const int g = blockIdx.x;           // 0..511
    const int row0 = g * S1_ROWS;

    __shared__ int slab[S1_ROWS];
    if (t < S1_ROWS) slab[t] = labels[row0 + t];
    __syncthreads();

    float acc[C_DIM][4];
#pragma unroll
    for (int c = 0; c < C_DIM; ++c)
#pragma unroll
        for (int j = 0; j < 4; ++j) acc[c][j] = 0.0f;

    const float4* sp = (const float4*)src + (size_t)row0 * 256 + t;
#pragma unroll 2
    for (int r = 0; r < S1_ROWS; ++r) {
        const int lab = slab[r];
        const float4 x = sp[(size_t)r * 256];
#pragma unroll
        for (int c = 0; c < C_DIM; ++c) {
            const float m = (lab == c) ? 1.0f : 0.0f;
            acc[c][0] = fmaf(m, x.x, acc[c][0]);
            acc[c][1] = fmaf(m, x.y, acc[c][1]);
            acc[c][2] = fmaf(m, x.z, acc[c][2]);
            acc[c][3] = fmaf(m, x.w, acc[c][3]);
        }
    }

    float4* dst = (float4*)(part + (size_t)g * (C_DIM * A_DIM)) + t;
#pragma unroll
    for (int c = 0; c < C_DIM; ++c)
        dst[c * 256] = make_float4(acc[c][0], acc[c][1], acc[c][2], acc[c][3]);

    if (t == 0) {
        int cnt[C_DIM] = {0, 0, 0, 0, 0, 0};
        for (int r = 0; r < S1_ROWS; ++r) {
            const int lab = slab[r];
            if ((unsigned)lab < C_DIM) ++cnt[lab];
        }
#pragma unroll
        for (int c = 0; c < C_DIM; ++c) atomicAdd(&counts[c], (float)cnt[c]);
    }
}

// ---- reduce 512 partials -> 16 ----
__global__ __launch_bounds__(256) void k_src_stage2a(
        const float* __restrict__ part, float* __restrict__ part2) {
    const int tid = blockIdx.x * 256 + threadIdx.x;   // 0..98303
    const int j = tid % (C_DIM * A_DIM);
    const int chunk = tid / (C_DIM * A_DIM);          // 0..15
    const float* p = part + (size_t)chunk * 32 * (C_DIM * A_DIM) + j;
    float s = 0.0f;
#pragma unroll 4
    for (int i = 0; i < 32; ++i) s += p[(size_t)i * (C_DIM * A_DIM)];
    part2[tid] = s;
}

// ---- 16 -> mean, write d_out[1..] ----
__global__ __launch_bounds__(256) void k_src_stage2b(
        const float* __restrict__ part2, const float* __restrict__ counts,
        float* __restrict__ out_mean) {
    const int j = blockIdx.x * 256 + threadIdx.x;     // 0..6143
    float s = 0.0f;
#pragma unroll
    for (int i = 0; i < 16; ++i) s += part2[i * (C_DIM * A_DIM) + j];
    const int c = j >> 10;
    out_mean[j] = s / fmaxf(counts[c], 1.0f);
}

// ---- main: contrast + loss1 numerator + per-class Z and N partials ----
__global__ __launch_bounds__(256) void k_main(
        const float* __restrict__ tarfeat, const float* __restrict__ tarout,
        const float* __restrict__ yn, float* __restrict__ accs) {
    __shared__ __align__(16) float s_yn[C_DIM * A_DIM];
    __shared__ float red[7][4][64];   // [quantity][wave][pixel-lane], conflict-free

    const int t = threadIdx.x;
#pragma unroll
    for (int i = 0; i < 24; ++i) s_yn[i * 256 + t] = yn[i * 256 + t];
    __syncthreads();

    const int wave = t >> 6;
    const int lane = t & 63;
    const int p = blockIdx.x * 64 + lane;     // pixel id
    const int b = p >> 14;
    const int hw = p & (HW - 1);
    const float* xp = tarfeat + ((size_t)b << 24) + hw;   // b*A*HW + hw
    const int a0 = wave * 256;                // each wave covers 256 channels

    float ns = 0.0f;
    float d0 = 0.0f, d1 = 0.0f, d2 = 0.0f, d3 = 0.0f, d4 = 0.0f, d5 = 0.0f;
#pragma unroll 2
    for (int k = 0; k < 64; ++k) {
        const int a = a0 + k * 4;
        float x0 = xp[(size_t)(a + 0) << 14];
        float x1 = xp[(size_t)(a + 1) << 14];
        float x2 = xp[(size_t)(a + 2) << 14];
        float x3 = xp[(size_t)(a + 3) << 14];
        float4 y0 = *(const float4*)(s_yn + 0 * A_DIM + a);
        float4 y1 = *(const float4*)(s_yn + 1 * A_DIM + a);
        float4 y2 = *(const float4*)(s_yn + 2 * A_DIM + a);
        float4 y3 = *(const float4*)(s_yn + 3 * A_DIM + a);
        float4 y4 = *(const float4*)(s_yn + 4 * A_DIM + a);
        float4 y5 = *(const float4*)(s_yn + 5 * A_DIM + a);
        ns = fmaf(x0, x0, ns); ns = fmaf(x1, x1, ns);
        ns = fmaf(x2, x2, ns); ns = fmaf(x3, x3, ns);
        d0 = fmaf(x0, y0.x, d0); d0 = fmaf(x1, y0.y, d0); d0 = fmaf(x2, y0.z, d0); d0 = fmaf(x3, y0.w, d0);
        d1 = fmaf(x0, y1.x, d1); d1 = fmaf(x1, y1.y, d1); d1 = fmaf(x2, y1.z, d1); d1 = fmaf(x3, y1.w, d1);
        d2 = fmaf(x0, y2.x, d2); d2 = fmaf(x1, y2.y, d2); d2 = fmaf(x2, y2.z, d2); d2 = fmaf(x3, y2.w, d2);
        d3 = fmaf(x0, y3.x, d3); d3 = fmaf(x1, y3.y, d3); d3 = fmaf(x2, y3.z, d3); d3 = fmaf(x3, y3.w, d3);
        d4 = fmaf(x0, y4.x, d4); d4 = fmaf(x1, y4.y, d4); d4 = fmaf(x2, y4.z, d4); d4 = fmaf(x3, y4.w, d4);
        d5 = fmaf(x0, y5.x, d5); d5 = fmaf(x1, y5.y, d5); d5 = fmaf(x2, y5.z, d5); d5 = fmaf(x3, y5.w, d5);
    }

    red[0][wave][lane] = ns;
    red[1][wave][lane] = d0;
    red[2][wave][lane] = d1;
    red[3][wave][lane] = d2;
    red[4][wave][lane] = d3;
    red[5][wave][lane] = d4;
    red[6][wave][lane] = d5;
    __syncthreads();

    if (t < 64) {   // wave 0 finalizes the block's 64 pixels
        float v[7];
#pragma unroll
        for (int i = 0; i < 7; ++i)
            v[i] = red[i][0][t] + red[i][1][t] + red[i][2][t] + red[i][3][t];
        const float inv = 1.0f / fmaxf(sqrtf(v[0]), 1e-12f);

        const int p2 = blockIdx.x * 64 + t;
        const int bb = p2 >> 14;
        const int hw2 = p2 & (HW - 1);
        float tv[C_DIM];
#pragma unroll
        for (int c = 0; c < C_DIM; ++c)
            tv[c] = tarout[((size_t)(bb * C_DIM + c) << 14) + hw2];

        float m = tv[0];
#pragma unroll
        for (int c = 1; c < C_DIM; ++c) m = fmaxf(m, tv[c]);
        const float em = __expf(m);
        float ex[C_DIM], ssum = 0.0f;
#pragma unroll
        for (int c = 0; c < C_DIM; ++c) { ex[c] = __expf(tv[c] - m); ssum += ex[c]; }

        float l1p = 0.0f;
        float zp[C_DIM], np[C_DIM];
#pragma unroll
        for (int c = 0; c < C_DIM; ++c) {
            const float bc = 1.0f - v[1 + c] * inv;
            l1p = fmaf(ex[c], bc, l1p);
            const float eraw = ex[c] * em;    // exp(tv[c])
            zp[c] = eraw;
            np[c] = eraw * bc;
        }
        float l1 = l1p / ssum;
        for (int off = 32; off > 0; off >>= 1) {
            l1 += __shfl_down(l1, off, 64);
#pragma unroll
            for (int c = 0; c < C_DIM; ++c) {
                zp[c] += __shfl_down(zp[c], off, 64);
                np[c] += __shfl_down(np[c], off, 64);
            }
        }
        if (t == 0) {
            atomicAdd(accs + 6, l1);
#pragma unroll
            for (int c = 0; c < C_DIM; ++c) {
                atomicAdd(accs + c, zp[c]);        // Z[c]
                atomicAdd(accs + 16 + c, np[c]);   // N[c]
            }
        }
    }
}

__global__ void k_final(const float* __restrict__ acc, float* __restrict__ out) {
    if (threadIdx.x == 0) {
        float l2 = 0.0f;
#pragma unroll
        for (int c = 0; c < C_DIM; ++c) l2 += acc[16 + c] / acc[c];
        out[0] = acc[6] / (float)N_PIX + l2 / (float)C_DIM;
    }
}

extern "C" void kernel_launch(void* const* d_in, const int* in_sizes, int n_in,
                              void* d_out, int out_size, void* d_ws, size_t ws_size,
                              hipStream_t stream) {
    const float* Proto   = (const float*)d_in[0];   // (6, 1024)
    const float* srcfeat = (const float*)d_in[1];   // (65536, 1024)
    const float* tarfeat = (const float*)d_in[2];   // (4, 1024, 128, 128)
    const float* tarout  = (const float*)d_in[3];   // (4, 6, 128, 128)
    const int*   labels  = (const int*)d_in[4];     // (65536,)
    float* out = (float*)d_out;                     // [loss, mean(6x1024)] = 6145

    float* w     = (float*)d_ws;
    float* accs  = w + WS_ACC;
    float* yn    = w + WS_YN;
    float* part1 = w + WS_P1;
    float* part2 = w + WS_P2;

    k_init<<<C_DIM + 1, 256, 0, stream>>>(Proto, yn, accs);
    k_src_stage1<<<S1_BLOCKS, 256, 0, stream>>>(srcfeat, labels, part1, accs + 8);
    k_src_stage2a<<<384, 256, 0, stream>>>(part1, part2);
    k_src_stage2b<<<24, 256, 0, stream>>>(part2, accs + 8, out + 1);
    k_main<<<N_PIX / 64, 256, 0, stream>>>(tarfeat, tarout, yn, accs);
    k_final<<<1, 64, 0, stream>>>(accs, out);
}